// Round 2
// baseline (765.782 us; speedup 1.0000x reference)
//
#include <hip/hip_runtime.h>
#include <hip/hip_bf16.h>

typedef short short8 __attribute__((ext_vector_type(8)));
typedef float f32x4 __attribute__((ext_vector_type(4)));

#define NEDGE 800000
#define HD    128
#define TM    64          // edges per block
#define LDA   264         // Abuf row stride in bf16 elems (128*2 + 8 pad)
#define LDS_S 132         // S (fp32) row stride
#define LDF   136         // fused bf16 row stride
#define LDH1  72
#define LDH2  40

__device__ __forceinline__ unsigned short f2bf(float f) {
    unsigned int u = __float_as_uint(f);
    unsigned int r = u + 0x7fffu + ((u >> 16) & 1u);   // RNE
    return (unsigned short)(r >> 16);
}

// Repack fp32 weight [K][N] (row-major) into bf16 per-lane MFMA B-fragment order:
// dst[((tile*KT + ks)*64 + l)*8 + j] = bf16(W[ks*32 + (l>>4)*8 + j][tile*16 + (l&15)])
__global__ void pack_w(const float* __restrict__ src,
                       unsigned short* __restrict__ dst,
                       int KT, int NT, int ncols) {
    int idx = blockIdx.x * 256 + threadIdx.x;
    int total = NT * KT * 64 * 8;
    if (idx >= total) return;
    int j = idx & 7;
    int l = (idx >> 3) & 63;
    int rem = idx >> 9;
    int s = rem % KT;
    int t = rem / KT;
    int k = s * 32 + ((l >> 4) << 3) + j;
    int n = t * 16 + (l & 15);
    dst[idx] = (n < ncols) ? f2bf(src[k * ncols + n]) : (unsigned short)0;
}

__global__ __launch_bounds__(256, 2)
void fused_relcls(const float* __restrict__ nf,
                  const float* __restrict__ desc,
                  const int* __restrict__ sub, const int* __restrict__ obj,
                  const unsigned short* __restrict__ wef, const unsigned short* __restrict__ wqf,
                  const unsigned short* __restrict__ wkf, const unsigned short* __restrict__ wvf,
                  const unsigned short* __restrict__ wc1f, const unsigned short* __restrict__ wc2f,
                  const unsigned short* __restrict__ wc3f,
                  const float* __restrict__ be, const float* __restrict__ bq,
                  const float* __restrict__ bk, const float* __restrict__ bv,
                  const float* __restrict__ bc1, const float* __restrict__ bc2,
                  const float* __restrict__ bc3,
                  float* __restrict__ out)
{
    __shared__ __align__(16) unsigned short Abuf[TM * LDA];   // 33792 B: geo -> non_geo -> S(fp32) -> fused
    __shared__ __align__(16) unsigned short h1Buf[TM * LDH1]; // 9216 B
    __shared__ __align__(16) unsigned short h2Buf[TM * LDH2]; // 5120 B
    __shared__ float rowstats[TM * 2];                        // 512 B: max, 1/sum per row
    __shared__ int sidx[TM], oidx[TM];

    const int t  = threadIdx.x;
    const int w  = t >> 6;       // wave 0..3
    const int l  = t & 63;
    const int cl = l & 15;       // col-in-tile (C/B) / row-in-tile (A)
    const int cq = l >> 4;       // quad
    const long e0 = (long)blockIdx.x * TM;

    if (t < TM) sidx[t] = sub[e0 + t];
    else if (t < 2 * TM) oidx[t - TM] = obj[e0 + t - TM];
    __syncthreads();

    // ---------------- stage geo = bf16([nf[sub] | nf[obj]]) ----------------
    {
        #pragma unroll
        for (int i = 0; i < 16; ++i) {
            int c = t + i * 256;               // 4096 chunks of 4 floats
            int e = c >> 6, half = (c >> 5) & 1, ci = c & 31;
            int idx = half ? oidx[e] : sidx[e];
            f32x4 v = *(const f32x4*)(nf + (long)idx * HD + ci * 4);
            ushort4 o;
            o.x = f2bf(v[0]); o.y = f2bf(v[1]); o.z = f2bf(v[2]); o.w = f2bf(v[3]);
            *(ushort4*)&Abuf[e * LDA + half * HD + ci * 4] = o;
        }
    }
    __syncthreads();

    // ---------------- phase 2: origin (We,be) + query (Wq,bq), A = geo ----------------
    f32x4 accO[4][2], accQ[4][2], accKV[4][2];
    {
        float b0 = be[w * 32 + cl],      b1 = be[w * 32 + 16 + cl];
        float q0 = bq[w * 32 + cl],      q1 = bq[w * 32 + 16 + cl];
        #pragma unroll
        for (int m = 0; m < 4; ++m) {
            accO[m][0] = (f32x4){b0, b0, b0, b0};
            accO[m][1] = (f32x4){b1, b1, b1, b1};
            accQ[m][0] = (f32x4){q0, q0, q0, q0};
            accQ[m][1] = (f32x4){q1, q1, q1, q1};
        }
        #pragma unroll
        for (int ks = 0; ks < 8; ++ks) {
            short8 a[4];
            #pragma unroll
            for (int m = 0; m < 4; ++m)
                a[m] = *(const short8*)&Abuf[(m * 16 + cl) * LDA + ks * 32 + cq * 8];
            short8 bwe[2], bwq[2];
            #pragma unroll
            for (int tt = 0; tt < 2; ++tt) {
                int off = (((w * 2 + tt) * 8 + ks) * 64 + l) * 8;
                bwe[tt] = *(const short8*)&wef[off];
                bwq[tt] = *(const short8*)&wqf[off];
            }
            #pragma unroll
            for (int m = 0; m < 4; ++m)
                #pragma unroll
                for (int tt = 0; tt < 2; ++tt) {
                    accO[m][tt] = __builtin_amdgcn_mfma_f32_16x16x32_bf16(a[m], bwe[tt], accO[m][tt], 0, 0, 0);
                    accQ[m][tt] = __builtin_amdgcn_mfma_f32_16x16x32_bf16(a[m], bwq[tt], accQ[m][tt], 0, 0, 0);
                }
        }
    }
    __syncthreads();

    // ---------------- stage non_geo = bf16([desc[sub] | desc[obj]]) ----------------
    {
        #pragma unroll
        for (int i = 0; i < 16; ++i) {
            int c = t + i * 256;
            int e = c >> 6, half = (c >> 5) & 1, ci = c & 31;
            int idx = half ? oidx[e] : sidx[e];
            f32x4 v = *(const f32x4*)(desc + (long)idx * HD + ci * 4);
            ushort4 o;
            o.x = f2bf(v[0]); o.y = f2bf(v[1]); o.z = f2bf(v[2]); o.w = f2bf(v[3]);
            *(ushort4*)&Abuf[e * LDA + half * HD + ci * 4] = o;
        }
    }
    __syncthreads();

    // ---------------- phase 4a: key (Wk,bk), A = non_geo; fold S = Q*K ----------------
    {
        float k0 = bk[w * 32 + cl], k1 = bk[w * 32 + 16 + cl];
        #pragma unroll
        for (int m = 0; m < 4; ++m) {
            accKV[m][0] = (f32x4){k0, k0, k0, k0};
            accKV[m][1] = (f32x4){k1, k1, k1, k1};
        }
        #pragma unroll
        for (int ks = 0; ks < 8; ++ks) {
            short8 a[4];
            #pragma unroll
            for (int m = 0; m < 4; ++m)
                a[m] = *(const short8*)&Abuf[(m * 16 + cl) * LDA + ks * 32 + cq * 8];
            short8 bw[2];
            #pragma unroll
            for (int tt = 0; tt < 2; ++tt)
                bw[tt] = *(const short8*)&wkf[(((w * 2 + tt) * 8 + ks) * 64 + l) * 8];
            #pragma unroll
            for (int m = 0; m < 4; ++m)
                #pragma unroll
                for (int tt = 0; tt < 2; ++tt)
                    accKV[m][tt] = __builtin_amdgcn_mfma_f32_16x16x32_bf16(a[m], bw[tt], accKV[m][tt], 0, 0, 0);
        }
        #pragma unroll
        for (int m = 0; m < 4; ++m)
            #pragma unroll
            for (int tt = 0; tt < 2; ++tt)
                accQ[m][tt] *= accKV[m][tt];     // S = q .* k  (same C-layout)
    }

    // ---------------- phase 4b: value (Wv,bv), A = non_geo ----------------
    {
        float v0 = bv[w * 32 + cl], v1 = bv[w * 32 + 16 + cl];
        #pragma unroll
        for (int m = 0; m < 4; ++m) {
            accKV[m][0] = (f32x4){v0, v0, v0, v0};
            accKV[m][1] = (f32x4){v1, v1, v1, v1};
        }
        #pragma unroll
        for (int ks = 0; ks < 8; ++ks) {
            short8 a[4];
            #pragma unroll
            for (int m = 0; m < 4; ++m)
                a[m] = *(const short8*)&Abuf[(m * 16 + cl) * LDA + ks * 32 + cq * 8];
            short8 bw[2];
            #pragma unroll
            for (int tt = 0; tt < 2; ++tt)
                bw[tt] = *(const short8*)&wvf[(((w * 2 + tt) * 8 + ks) * 64 + l) * 8];
            #pragma unroll
            for (int m = 0; m < 4; ++m)
                #pragma unroll
                for (int tt = 0; tt < 2; ++tt)
                    accKV[m][tt] = __builtin_amdgcn_mfma_f32_16x16x32_bf16(a[m], bw[tt], accKV[m][tt], 0, 0, 0);
        }
    }
    __syncthreads();   // all waves done reading non_geo; Abuf now reusable

    // ---------------- phase 5: spill S to LDS (fp32) for row reduction ----------------
    {
        float* Sbuf = (float*)Abuf;
        #pragma unroll
        for (int m = 0; m < 4; ++m)
            #pragma unroll
            for (int tt = 0; tt < 2; ++tt)
                #pragma unroll
                for (int r = 0; r < 4; ++r) {
                    int row = m * 16 + cq * 4 + r;
                    int col = w * 32 + tt * 16 + cl;
                    Sbuf[row * LDS_S + col] = accQ[m][tt][r];
                }
    }
    __syncthreads();

    // ---------------- phase 6: per-row max & sum(exp) ----------------
    {
        const float* Sbuf = (const float*)Abuf;
        int r = t >> 2, q = t & 3;
        const f32x4* Srow = (const f32x4*)(Sbuf + r * LDS_S + q * 32);
        float mx = -1e30f;
        #pragma unroll
        for (int u = 0; u < 8; ++u) {
            f32x4 x = Srow[u];
            mx = fmaxf(mx, fmaxf(fmaxf(x[0], x[1]), fmaxf(x[2], x[3])));
        }
        mx = fmaxf(mx, __shfl_xor(mx, 1));
        mx = fmaxf(mx, __shfl_xor(mx, 2));
        float sm = 0.f;
        #pragma unroll
        for (int u = 0; u < 8; ++u) {
            f32x4 x = Srow[u];
            sm += __expf(x[0] - mx) + __expf(x[1] - mx) + __expf(x[2] - mx) + __expf(x[3] - mx);
        }
        sm += __shfl_xor(sm, 1);
        sm += __shfl_xor(sm, 2);
        if (q == 0) { rowstats[r * 2] = mx; rowstats[r * 2 + 1] = 1.0f / sm; }
    }
    __syncthreads();

    // ---------------- phase 7: fused = V*alpha + O  -> LDS bf16 (A-layout) ----------------
    {
        unsigned short* fusedBuf = Abuf;   // stride LDF
        #pragma unroll
        for (int m = 0; m < 4; ++m)
            #pragma unroll
            for (int r = 0; r < 4; ++r) {
                int row = m * 16 + cq * 4 + r;
                float mx  = rowstats[row * 2];
                float inv = rowstats[row * 2 + 1];
                #pragma unroll
                for (int tt = 0; tt < 2; ++tt) {
                    int col = w * 32 + tt * 16 + cl;
                    float alpha = __expf(accQ[m][tt][r] - mx) * inv;
                    float f = accKV[m][tt][r] * alpha + accO[m][tt][r];
                    fusedBuf[row * LDF + col] = f2bf(f);
                }
            }
    }
    __syncthreads();

    // ---------------- classifier L1: [64,128]@[128,64] + relu ----------------
    {
        const unsigned short* fusedBuf = Abuf;
        float b1 = bc1[w * 16 + cl];
        f32x4 acc[4];
        #pragma unroll
        for (int m = 0; m < 4; ++m) acc[m] = (f32x4){b1, b1, b1, b1};
        #pragma unroll
        for (int ks = 0; ks < 4; ++ks) {
            short8 a[4];
            #pragma unroll
            for (int m = 0; m < 4; ++m)
                a[m] = *(const short8*)&fusedBuf[(m * 16 + cl) * LDF + ks * 32 + cq * 8];
            short8 bw = *(const short8*)&wc1f[((w * 4 + ks) * 64 + l) * 8];
            #pragma unroll
            for (int m = 0; m < 4; ++m)
                acc[m] = __builtin_amdgcn_mfma_f32_16x16x32_bf16(a[m], bw, acc[m], 0, 0, 0);
        }
        #pragma unroll
        for (int m = 0; m < 4; ++m)
            #pragma unroll
            for (int r = 0; r < 4; ++r)
                h1Buf[(m * 16 + cq * 4 + r) * LDH1 + w * 16 + cl] = f2bf(fmaxf(acc[m][r], 0.f));
    }
    __syncthreads();

    // ---------------- classifier L2: [64,64]@[64,32] (no relu) ----------------
    {
        int tn = w & 1, mh = w >> 1;
        float b2 = bc2[tn * 16 + cl];
        f32x4 acc[2];
        acc[0] = (f32x4){b2, b2, b2, b2};
        acc[1] = (f32x4){b2, b2, b2, b2};
        #pragma unroll
        for (int ks = 0; ks < 2; ++ks) {
            short8 a[2];
            #pragma unroll
            for (int mm = 0; mm < 2; ++mm)
                a[mm] = *(const short8*)&h1Buf[((mh * 2 + mm) * 16 + cl) * LDH1 + ks * 32 + cq * 8];
            short8 bw = *(const short8*)&wc2f[((tn * 2 + ks) * 64 + l) * 8];
            #pragma unroll
            for (int mm = 0; mm < 2; ++mm)
                acc[mm] = __builtin_amdgcn_mfma_f32_16x16x32_bf16(a[mm], bw, acc[mm], 0, 0, 0);
        }
        #pragma unroll
        for (int mm = 0; mm < 2; ++mm)
            #pragma unroll
            for (int r = 0; r < 4; ++r)
                h2Buf[((mh * 2 + mm) * 16 + cq * 4 + r) * LDH2 + tn * 16 + cl] = f2bf(acc[mm][r]);
    }
    __syncthreads();

    // ---------------- classifier L3: [64,32]@[32,26] -> out (fp32) ----------------
    {
        f32x4 acc[2];
        #pragma unroll
        for (int tt = 0; tt < 2; ++tt) {
            int col = tt * 16 + cl;
            float b3 = (col < 26) ? bc3[col] : 0.f;
            acc[tt] = (f32x4){b3, b3, b3, b3};
        }
        short8 a = *(const short8*)&h2Buf[(w * 16 + cl) * LDH2 + cq * 8];
        #pragma unroll
        for (int tt = 0; tt < 2; ++tt)
            acc[tt] = __builtin_amdgcn_mfma_f32_16x16x32_bf16(a, *(const short8*)&wc3f[(tt * 64 + l) * 8], acc[tt], 0, 0, 0);
        #pragma unroll
        for (int tt = 0; tt < 2; ++tt) {
            int col = tt * 16 + cl;
            if (col < 26) {
                #pragma unroll
                for (int r = 0; r < 4; ++r) {
                    long row = e0 + w * 16 + cq * 4 + r;
                    out[row * 26 + col] = acc[tt][r];
                }
            }
        }
    }
}

extern "C" void kernel_launch(void* const* d_in, const int* in_sizes, int n_in,
                              void* d_out, int out_size, void* d_ws, size_t ws_size,
                              hipStream_t stream) {
    const float* nf   = (const float*)d_in[0];
    const float* desc = (const float*)d_in[1];
    const int* sub = (const int*)d_in[2];
    const int* obj = (const int*)d_in[3];
    const float* We  = (const float*)d_in[4];
    const float* be  = (const float*)d_in[5];
    const float* Wq  = (const float*)d_in[6];
    const float* bq  = (const float*)d_in[7];
    const float* Wk  = (const float*)d_in[8];
    const float* bk  = (const float*)d_in[9];
    const float* Wv  = (const float*)d_in[10];
    const float* bv  = (const float*)d_in[11];
    const float* Wc1 = (const float*)d_in[12];
    const float* bc1 = (const float*)d_in[13];
    const float* Wc2 = (const float*)d_in[14];
    const float* bc2 = (const float*)d_in[15];
    const float* Wc3 = (const float*)d_in[16];
    const float* bc3 = (const float*)d_in[17];

    unsigned short* ws = (unsigned short*)d_ws;
    unsigned short* wef  = ws;                 // 8*8*64*8  = 32768 elems
    unsigned short* wqf  = ws + 32768;
    unsigned short* wkf  = ws + 65536;
    unsigned short* wvf  = ws + 98304;
    unsigned short* wc1f = ws + 131072;        // 4*4*64*8 = 8192
    unsigned short* wc2f = ws + 139264;        // 2*2*64*8 = 2048
    unsigned short* wc3f = ws + 141312;        // 1*2*64*8 = 1024

    pack_w<<<128, 256, 0, stream>>>(We,  wef,  8, 8, 128);
    pack_w<<<128, 256, 0, stream>>>(Wq,  wqf,  8, 8, 128);
    pack_w<<<128, 256, 0, stream>>>(Wk,  wkf,  8, 8, 128);
    pack_w<<<128, 256, 0, stream>>>(Wv,  wvf,  8, 8, 128);
    pack_w<<<32,  256, 0, stream>>>(Wc1, wc1f, 4, 4, 64);
    pack_w<<<8,   256, 0, stream>>>(Wc2, wc2f, 2, 2, 32);
    pack_w<<<4,   256, 0, stream>>>(Wc3, wc3f, 1, 2, 26);

    fused_relcls<<<NEDGE / TM, 256, 0, stream>>>(
        nf, desc, sub, obj,
        wef, wqf, wkf, wvf, wc1f, wc2f, wc3f,
        be, bq, bk, bv, bc1, bc2, bc3,
        (float*)d_out);
}

// Round 3
// 728.429 us; speedup vs baseline: 1.0513x; 1.0513x over previous
//
#include <hip/hip_runtime.h>
#include <hip/hip_bf16.h>

typedef short short8 __attribute__((ext_vector_type(8)));
typedef float f32x4 __attribute__((ext_vector_type(4)));

#define NEDGE 800000
#define HD    128
#define TM    64          // edges per block
#define LDA   264         // Abuf row stride in bf16 elems (128*2 + 8 pad)
#define LDS_S 132         // S (fp32) row stride
#define LDF   136         // fused bf16 row stride
#define LDH1  72
#define LDH2  40

__device__ __forceinline__ unsigned short f2bf(float f) {
    unsigned int u = __float_as_uint(f);
    unsigned int r = u + 0x7fffu + ((u >> 16) & 1u);   // RNE
    return (unsigned short)(r >> 16);
}

// One kernel packs all 7 fp32 weights [K][N] into bf16 per-lane MFMA B-fragment order:
// dst[((tile*KT + ks)*64 + l)*8 + j] = bf16(W[ks*32 + (l>>4)*8 + j][tile*16 + (l&15)])
__global__ void pack_all(const float* __restrict__ We, const float* __restrict__ Wq,
                         const float* __restrict__ Wk, const float* __restrict__ Wv,
                         const float* __restrict__ Wc1, const float* __restrict__ Wc2,
                         const float* __restrict__ Wc3,
                         unsigned short* __restrict__ ws) {
    int b = blockIdx.x;
    const float* src; unsigned short* dst; int KT, NT, ncols;
    if (b < 512) {
        int sel = b >> 7;
        src = sel == 0 ? We : sel == 1 ? Wq : sel == 2 ? Wk : Wv;
        dst = ws + sel * 32768;
        KT = 8; NT = 8; ncols = 128; b &= 127;
    } else if (b < 544) { src = Wc1; dst = ws + 131072; KT = 4; NT = 4; ncols = 64; b -= 512; }
    else if (b < 552)   { src = Wc2; dst = ws + 139264; KT = 2; NT = 2; ncols = 32; b -= 544; }
    else                { src = Wc3; dst = ws + 141312; KT = 1; NT = 2; ncols = 26; b -= 552; }
    int idx = b * 256 + threadIdx.x;
    int total = NT * KT * 64 * 8;
    if (idx >= total) return;
    int j = idx & 7;
    int l = (idx >> 3) & 63;
    int rem = idx >> 9;
    int s = rem % KT;
    int t = rem / KT;
    int k = s * 32 + ((l >> 4) << 3) + j;
    int n = t * 16 + (l & 15);
    dst[idx] = (n < ncols) ? f2bf(src[k * ncols + n]) : (unsigned short)0;
}

__global__ __launch_bounds__(256, 4)
void fused_relcls(const float* __restrict__ nf,
                  const float* __restrict__ desc,
                  const int* __restrict__ sub, const int* __restrict__ obj,
                  const unsigned short* __restrict__ wef, const unsigned short* __restrict__ wqf,
                  const unsigned short* __restrict__ wkf, const unsigned short* __restrict__ wvf,
                  const unsigned short* __restrict__ wc1f, const unsigned short* __restrict__ wc2f,
                  const unsigned short* __restrict__ wc3f,
                  const float* __restrict__ be, const float* __restrict__ bq,
                  const float* __restrict__ bk, const float* __restrict__ bv,
                  const float* __restrict__ bc1, const float* __restrict__ bc2,
                  const float* __restrict__ bc3,
                  float* __restrict__ out)
{
    // 33792 B Abuf serves as: geo -> non_geo -> S(fp32) -> fused(17408 B) + h1(9216 B) + h2(5120 B)
    __shared__ __align__(16) unsigned short Abuf[TM * LDA];
    __shared__ float rowstats[TM * 2];                        // max, 1/sum per row
    unsigned short* h1Buf = Abuf + 8704;    // byte off 17408, after fused region
    unsigned short* h2Buf = Abuf + 13312;   // byte off 26624

    const int t  = threadIdx.x;
    const int w  = t >> 6;       // wave 0..3
    const int l  = t & 63;
    const int cl = l & 15;       // col-in-tile (C/B) / row-in-tile (A)
    const int cq = l >> 4;       // quad
    const long e0 = (long)blockIdx.x * TM;
    const int wu = __builtin_amdgcn_readfirstlane(w);
    const int half = l >> 5;     // lanes 0-31: sub half, 32-63: obj half
    const int ci   = l & 31;

    // ---------------- stage geo = bf16([nf[sub] | nf[obj]]) ----------------
    {
        #pragma unroll
        for (int i = 0; i < 16; ++i) {
            int e = wu + 4 * i;                 // wave-uniform edge
            int si = sub[e0 + e];               // scalar loads
            int oi = obj[e0 + e];
            int idx = half ? oi : si;
            f32x4 v = *(const f32x4*)(nf + (long)idx * HD + ci * 4);
            ushort4 o;
            o.x = f2bf(v[0]); o.y = f2bf(v[1]); o.z = f2bf(v[2]); o.w = f2bf(v[3]);
            *(ushort4*)&Abuf[e * LDA + half * HD + ci * 4] = o;
        }
    }
    __syncthreads();

    // ---------------- phase 2: origin (We,be) + query (Wq,bq), A = geo ----------------
    f32x4 accO[4][2], accQ[4][2], accKV[4][2];
    {
        float b0 = be[w * 32 + cl],      b1 = be[w * 32 + 16 + cl];
        float q0 = bq[w * 32 + cl],      q1 = bq[w * 32 + 16 + cl];
        #pragma unroll
        for (int m = 0; m < 4; ++m) {
            accO[m][0] = (f32x4){b0, b0, b0, b0};
            accO[m][1] = (f32x4){b1, b1, b1, b1};
            accQ[m][0] = (f32x4){q0, q0, q0, q0};
            accQ[m][1] = (f32x4){q1, q1, q1, q1};
        }
        #pragma unroll
        for (int ks = 0; ks < 8; ++ks) {
            short8 a[4];
            #pragma unroll
            for (int m = 0; m < 4; ++m)
                a[m] = *(const short8*)&Abuf[(m * 16 + cl) * LDA + ks * 32 + cq * 8];
            short8 bwe[2], bwq[2];
            #pragma unroll
            for (int tt = 0; tt < 2; ++tt) {
                int off = (((w * 2 + tt) * 8 + ks) * 64 + l) * 8;
                bwe[tt] = *(const short8*)&wef[off];
                bwq[tt] = *(const short8*)&wqf[off];
            }
            #pragma unroll
            for (int m = 0; m < 4; ++m)
                #pragma unroll
                for (int tt = 0; tt < 2; ++tt) {
                    accO[m][tt] = __builtin_amdgcn_mfma_f32_16x16x32_bf16(a[m], bwe[tt], accO[m][tt], 0, 0, 0);
                    accQ[m][tt] = __builtin_amdgcn_mfma_f32_16x16x32_bf16(a[m], bwq[tt], accQ[m][tt], 0, 0, 0);
                }
        }
    }
    __syncthreads();

    // ---------------- stage non_geo = bf16([desc[sub] | desc[obj]]) ----------------
    {
        #pragma unroll
        for (int i = 0; i < 16; ++i) {
            int e = wu + 4 * i;
            int si = sub[e0 + e];
            int oi = obj[e0 + e];
            int idx = half ? oi : si;
            f32x4 v = *(const f32x4*)(desc + (long)idx * HD + ci * 4);
            ushort4 o;
            o.x = f2bf(v[0]); o.y = f2bf(v[1]); o.z = f2bf(v[2]); o.w = f2bf(v[3]);
            *(ushort4*)&Abuf[e * LDA + half * HD + ci * 4] = o;
        }
    }
    __syncthreads();

    // ---------------- phase 4a: key (Wk,bk), A = non_geo; fold S = Q*K ----------------
    {
        float k0 = bk[w * 32 + cl], k1 = bk[w * 32 + 16 + cl];
        #pragma unroll
        for (int m = 0; m < 4; ++m) {
            accKV[m][0] = (f32x4){k0, k0, k0, k0};
            accKV[m][1] = (f32x4){k1, k1, k1, k1};
        }
        #pragma unroll
        for (int ks = 0; ks < 8; ++ks) {
            short8 a[4];
            #pragma unroll
            for (int m = 0; m < 4; ++m)
                a[m] = *(const short8*)&Abuf[(m * 16 + cl) * LDA + ks * 32 + cq * 8];
            short8 bw[2];
            #pragma unroll
            for (int tt = 0; tt < 2; ++tt)
                bw[tt] = *(const short8*)&wkf[(((w * 2 + tt) * 8 + ks) * 64 + l) * 8];
            #pragma unroll
            for (int m = 0; m < 4; ++m)
                #pragma unroll
                for (int tt = 0; tt < 2; ++tt)
                    accKV[m][tt] = __builtin_amdgcn_mfma_f32_16x16x32_bf16(a[m], bw[tt], accKV[m][tt], 0, 0, 0);
        }
        #pragma unroll
        for (int m = 0; m < 4; ++m)
            #pragma unroll
            for (int tt = 0; tt < 2; ++tt)
                accQ[m][tt] *= accKV[m][tt];     // S = q .* k  (same C-layout)
    }

    // ---------------- phase 4b: value (Wv,bv), A = non_geo ----------------
    {
        float v0 = bv[w * 32 + cl], v1 = bv[w * 32 + 16 + cl];
        #pragma unroll
        for (int m = 0; m < 4; ++m) {
            accKV[m][0] = (f32x4){v0, v0, v0, v0};
            accKV[m][1] = (f32x4){v1, v1, v1, v1};
        }
        #pragma unroll
        for (int ks = 0; ks < 8; ++ks) {
            short8 a[4];
            #pragma unroll
            for (int m = 0; m < 4; ++m)
                a[m] = *(const short8*)&Abuf[(m * 16 + cl) * LDA + ks * 32 + cq * 8];
            short8 bw[2];
            #pragma unroll
            for (int tt = 0; tt < 2; ++tt)
                bw[tt] = *(const short8*)&wvf[(((w * 2 + tt) * 8 + ks) * 64 + l) * 8];
            #pragma unroll
            for (int m = 0; m < 4; ++m)
                #pragma unroll
                for (int tt = 0; tt < 2; ++tt)
                    accKV[m][tt] = __builtin_amdgcn_mfma_f32_16x16x32_bf16(a[m], bw[tt], accKV[m][tt], 0, 0, 0);
        }
    }
    __syncthreads();   // all waves done reading non_geo; Abuf now reusable

    // ---------------- phase 5: spill S to LDS (fp32) for row reduction ----------------
    {
        float* Sbuf = (float*)Abuf;
        #pragma unroll
        for (int m = 0; m < 4; ++m)
            #pragma unroll
            for (int tt = 0; tt < 2; ++tt)
                #pragma unroll
                for (int r = 0; r < 4; ++r) {
                    int row = m * 16 + cq * 4 + r;
                    int col = w * 32 + tt * 16 + cl;
                    Sbuf[row * LDS_S + col] = accQ[m][tt][r];
                }
    }
    __syncthreads();

    // ---------------- phase 6: per-row max & sum(exp) ----------------
    {
        const float* Sbuf = (const float*)Abuf;
        int r = t >> 2, q = t & 3;
        const f32x4* Srow = (const f32x4*)(Sbuf + r * LDS_S + q * 32);
        float mx = -1e30f;
        #pragma unroll
        for (int u = 0; u < 8; ++u) {
            f32x4 x = Srow[u];
            mx = fmaxf(mx, fmaxf(fmaxf(x[0], x[1]), fmaxf(x[2], x[3])));
        }
        mx = fmaxf(mx, __shfl_xor(mx, 1));
        mx = fmaxf(mx, __shfl_xor(mx, 2));
        float sm = 0.f;
        #pragma unroll
        for (int u = 0; u < 8; ++u) {
            f32x4 x = Srow[u];
            sm += __expf(x[0] - mx) + __expf(x[1] - mx) + __expf(x[2] - mx) + __expf(x[3] - mx);
        }
        sm += __shfl_xor(sm, 1);
        sm += __shfl_xor(sm, 2);
        if (q == 0) { rowstats[r * 2] = mx; rowstats[r * 2 + 1] = 1.0f / sm; }
    }
    __syncthreads();

    // ---------------- phase 7: fused = V*alpha + O  -> LDS bf16 (A-layout) ----------------
    {
        unsigned short* fusedBuf = Abuf;   // stride LDF, 17408 B
        #pragma unroll
        for (int m = 0; m < 4; ++m)
            #pragma unroll
            for (int r = 0; r < 4; ++r) {
                int row = m * 16 + cq * 4 + r;
                float mx  = rowstats[row * 2];
                float inv = rowstats[row * 2 + 1];
                #pragma unroll
                for (int tt = 0; tt < 2; ++tt) {
                    int col = w * 32 + tt * 16 + cl;
                    float alpha = __expf(accQ[m][tt][r] - mx) * inv;
                    float f = accKV[m][tt][r] * alpha + accO[m][tt][r];
                    fusedBuf[row * LDF + col] = f2bf(f);
                }
            }
    }
    __syncthreads();

    // ---------------- classifier L1: [64,128]@[128,64] + relu ----------------
    {
        const unsigned short* fusedBuf = Abuf;
        float b1 = bc1[w * 16 + cl];
        f32x4 acc[4];
        #pragma unroll
        for (int m = 0; m < 4; ++m) acc[m] = (f32x4){b1, b1, b1, b1};
        #pragma unroll
        for (int ks = 0; ks < 4; ++ks) {
            short8 a[4];
            #pragma unroll
            for (int m = 0; m < 4; ++m)
                a[m] = *(const short8*)&fusedBuf[(m * 16 + cl) * LDF + ks * 32 + cq * 8];
            short8 bw = *(const short8*)&wc1f[((w * 4 + ks) * 64 + l) * 8];
            #pragma unroll
            for (int m = 0; m < 4; ++m)
                acc[m] = __builtin_amdgcn_mfma_f32_16x16x32_bf16(a[m], bw, acc[m], 0, 0, 0);
        }
        #pragma unroll
        for (int m = 0; m < 4; ++m)
            #pragma unroll
            for (int r = 0; r < 4; ++r)
                h1Buf[(m * 16 + cq * 4 + r) * LDH1 + w * 16 + cl] = f2bf(fmaxf(acc[m][r], 0.f));
    }
    __syncthreads();

    // ---------------- classifier L2: [64,64]@[64,32] (no relu) ----------------
    {
        int tn = w & 1, mh = w >> 1;
        float b2 = bc2[tn * 16 + cl];
        f32x4 acc[2];
        acc[0] = (f32x4){b2, b2, b2, b2};
        acc[1] = (f32x4){b2, b2, b2, b2};
        #pragma unroll
        for (int ks = 0; ks < 2; ++ks) {
            short8 a[2];
            #pragma unroll
            for (int mm = 0; mm < 2; ++mm)
                a[mm] = *(const short8*)&h1Buf[((mh * 2 + mm) * 16 + cl) * LDH1 + ks * 32 + cq * 8];
            short8 bw = *(const short8*)&wc2f[((tn * 2 + ks) * 64 + l) * 8];
            #pragma unroll
            for (int mm = 0; mm < 2; ++mm)
                acc[mm] = __builtin_amdgcn_mfma_f32_16x16x32_bf16(a[mm], bw, acc[mm], 0, 0, 0);
        }
        #pragma unroll
        for (int mm = 0; mm < 2; ++mm)
            #pragma unroll
            for (int r = 0; r < 4; ++r)
                h2Buf[((mh * 2 + mm) * 16 + cq * 4 + r) * LDH2 + tn * 16 + cl] = f2bf(acc[mm][r]);
    }
    __syncthreads();

    // ---------------- classifier L3: [64,32]@[32,26] -> out (fp32) ----------------
    {
        f32x4 acc[2];
        #pragma unroll
        for (int tt = 0; tt < 2; ++tt) {
            int col = tt * 16 + cl;
            float b3 = (col < 26) ? bc3[col] : 0.f;
            acc[tt] = (f32x4){b3, b3, b3, b3};
        }
        short8 a = *(const short8*)&h2Buf[(w * 16 + cl) * LDH2 + cq * 8];
        #pragma unroll
        for (int tt = 0; tt < 2; ++tt)
            acc[tt] = __builtin_amdgcn_mfma_f32_16x16x32_bf16(a, *(const short8*)&wc3f[(tt * 64 + l) * 8], acc[tt], 0, 0, 0);
        #pragma unroll
        for (int tt = 0; tt < 2; ++tt) {
            int col = tt * 16 + cl;
            if (col < 26) {
                #pragma unroll
                for (int r = 0; r < 4; ++r) {
                    long row = e0 + w * 16 + cq * 4 + r;
                    out[row * 26 + col] = acc[tt][r];
                }
            }
        }
    }
}

extern "C" void kernel_launch(void* const* d_in, const int* in_sizes, int n_in,
                              void* d_out, int out_size, void* d_ws, size_t ws_size,
                              hipStream_t stream) {
    const float* nf   = (const float*)d_in[0];
    const float* desc = (const float*)d_in[1];
    const int* sub = (const int*)d_in[2];
    const int* obj = (const int*)d_in[3];
    const float* We  = (const float*)d_in[4];
    const float* be  = (const float*)d_in[5];
    const float* Wq  = (const float*)d_in[6];
    const float* bq  = (const float*)d_in[7];
    const float* Wk  = (const float*)d_in[8];
    const float* bk  = (const float*)d_in[9];
    const float* Wv  = (const float*)d_in[10];
    const float* bv  = (const float*)d_in[11];
    const float* Wc1 = (const float*)d_in[12];
    const float* bc1 = (const float*)d_in[13];
    const float* Wc2 = (const float*)d_in[14];
    const float* bc2 = (const float*)d_in[15];
    const float* Wc3 = (const float*)d_in[16];
    const float* bc3 = (const float*)d_in[17];

    unsigned short* ws = (unsigned short*)d_ws;
    unsigned short* wef  = ws;                 // 8*8*64*8  = 32768 elems
    unsigned short* wqf  = ws + 32768;
    unsigned short* wkf  = ws + 65536;
    unsigned short* wvf  = ws + 98304;
    unsigned short* wc1f = ws + 131072;        // 4*4*64*8 = 8192
    unsigned short* wc2f = ws + 139264;        // 2*2*64*8 = 2048
    unsigned short* wc3f = ws + 141312;        // 1*2*64*8 = 1024

    pack_all<<<556, 256, 0, stream>>>(We, Wq, Wk, Wv, Wc1, Wc2, Wc3, ws);

    fused_relcls<<<NEDGE / TM, 256, 0, stream>>>(
        nf, desc, sub, obj,
        wef, wqf, wkf, wvf, wc1f, wc2f, wc3f,
        be, bq, bk, bv, bc1, bc2, bc3,
        (float*)d_out);
}

// Round 4
// 590.333 us; speedup vs baseline: 1.2972x; 1.2339x over previous
//
#include <hip/hip_runtime.h>
#include <hip/hip_bf16.h>

typedef short short8 __attribute__((ext_vector_type(8)));
typedef float f32x4 __attribute__((ext_vector_type(4)));

#define NEDGE 800000
#define HD    128
#define TM    64          // edges per block
#define LDA   264         // Abuf row stride in bf16 elems (128*2 + 8 pad)
#define LDF   136         // fused bf16 row stride
#define LDH1  72
#define LDH2  40

__device__ __forceinline__ unsigned short f2bf(float f) {
    unsigned int u = __float_as_uint(f);
    unsigned int r = u + 0x7fffu + ((u >> 16) & 1u);   // RNE
    return (unsigned short)(r >> 16);
}
__device__ __forceinline__ float bf2f(unsigned short u) {
    union { unsigned int i; float f; } v; v.i = ((unsigned int)u) << 16; return v.f;
}

// One kernel packs all 7 fp32 weights [K][N] into bf16 per-lane MFMA B-fragment order:
// dst[((tile*KT + ks)*64 + l)*8 + j] = bf16(W[ks*32 + (l>>4)*8 + j][tile*16 + (l&15)])
__global__ void pack_all(const float* __restrict__ We, const float* __restrict__ Wq,
                         const float* __restrict__ Wk, const float* __restrict__ Wv,
                         const float* __restrict__ Wc1, const float* __restrict__ Wc2,
                         const float* __restrict__ Wc3,
                         unsigned short* __restrict__ ws) {
    int b = blockIdx.x;
    const float* src; unsigned short* dst; int KT, NT, ncols;
    if (b < 512) {
        int sel = b >> 7;
        src = sel == 0 ? We : sel == 1 ? Wq : sel == 2 ? Wk : Wv;
        dst = ws + sel * 32768;
        KT = 8; NT = 8; ncols = 128; b &= 127;
    } else if (b < 544) { src = Wc1; dst = ws + 131072; KT = 4; NT = 4; ncols = 64; b -= 512; }
    else if (b < 552)   { src = Wc2; dst = ws + 139264; KT = 2; NT = 2; ncols = 32; b -= 544; }
    else                { src = Wc3; dst = ws + 141312; KT = 1; NT = 2; ncols = 26; b -= 552; }
    int idx = b * 256 + threadIdx.x;
    int total = NT * KT * 64 * 8;
    if (idx >= total) return;
    int j = idx & 7;
    int l = (idx >> 3) & 63;
    int rem = idx >> 9;
    int s = rem % KT;
    int t = rem / KT;
    int k = s * 32 + ((l >> 4) << 3) + j;
    int n = t * 16 + (l & 15);
    dst[idx] = (n < ncols) ? f2bf(src[k * ncols + n]) : (unsigned short)0;
}

__global__ __launch_bounds__(256, 3)
void fused_relcls(const float* __restrict__ nf,
                  const float* __restrict__ desc,
                  const int* __restrict__ sub, const int* __restrict__ obj,
                  const unsigned short* __restrict__ wef, const unsigned short* __restrict__ wqf,
                  const unsigned short* __restrict__ wkf, const unsigned short* __restrict__ wvf,
                  const unsigned short* __restrict__ wc1f, const unsigned short* __restrict__ wc2f,
                  const unsigned short* __restrict__ wc3f,
                  const float* __restrict__ be, const float* __restrict__ bq,
                  const float* __restrict__ bk, const float* __restrict__ bv,
                  const float* __restrict__ bc1, const float* __restrict__ bc2,
                  const float* __restrict__ bc3,
                  float* __restrict__ out)
{
    // Abuf: geo -> non_geo -> fused(17408 B) + h1(9216 B) + h2(5120 B)
    __shared__ __align__(16) unsigned short Abuf[TM * LDA];   // 33792 B
    __shared__ __align__(16) unsigned int   Obuf[256 * 16];   // 16384 B: per-lane bf16 O scratch
    __shared__ float smx[TM * 4], ssm[TM * 4];                // 2048 B: per-wave softmax partials
    unsigned short* h1Buf = Abuf + 8704;    // byte off 17408
    unsigned short* h2Buf = Abuf + 13312;   // byte off 26624

    const int t  = threadIdx.x;
    const int w  = t >> 6;       // wave 0..3 (owns cols [w*32, w*32+32))
    const int l  = t & 63;
    const int cl = l & 15;       // col-in-tile (C/B) / row-in-tile (A)
    const int cq = l >> 4;       // quad
    const long e0 = (long)blockIdx.x * TM;
    const int wu = __builtin_amdgcn_readfirstlane(w);
    const int half = l >> 5;     // lanes 0-31: sub half, 32-63: obj half
    const int ci   = l & 31;

    // ---------------- stage geo = bf16([nf[sub] | nf[obj]]) ----------------
    {
        #pragma unroll
        for (int i = 0; i < 16; ++i) {
            int e = wu + 4 * i;                 // wave-uniform edge
            int si = sub[e0 + e];
            int oi = obj[e0 + e];
            int idx = half ? oi : si;
            f32x4 v = *(const f32x4*)(nf + (long)idx * HD + ci * 4);
            ushort4 o;
            o.x = f2bf(v[0]); o.y = f2bf(v[1]); o.z = f2bf(v[2]); o.w = f2bf(v[3]);
            *(ushort4*)&Abuf[e * LDA + half * HD + ci * 4] = o;
        }
    }
    __syncthreads();   // B1

    f32x4 acc0[4][2], acc1[4][2];   // only TWO live accumulator matrices -> 64 regs peak

    // ---------------- O-phase: origin = geo@We + be, then park in LDS as bf16 ----------------
    {
        float b0 = be[w * 32 + cl], b1 = be[w * 32 + 16 + cl];
        #pragma unroll
        for (int m = 0; m < 4; ++m) {
            acc0[m][0] = (f32x4){b0, b0, b0, b0};
            acc0[m][1] = (f32x4){b1, b1, b1, b1};
        }
        #pragma unroll
        for (int ks = 0; ks < 8; ++ks) {
            short8 a[4];
            #pragma unroll
            for (int m = 0; m < 4; ++m)
                a[m] = *(const short8*)&Abuf[(m * 16 + cl) * LDA + ks * 32 + cq * 8];
            short8 bw[2];
            #pragma unroll
            for (int tt = 0; tt < 2; ++tt)
                bw[tt] = *(const short8*)&wef[(((w * 2 + tt) * 8 + ks) * 64 + l) * 8];
            #pragma unroll
            for (int m = 0; m < 4; ++m)
                #pragma unroll
                for (int tt = 0; tt < 2; ++tt)
                    acc0[m][tt] = __builtin_amdgcn_mfma_f32_16x16x32_bf16(a[m], bw[tt], acc0[m][tt], 0, 0, 0);
        }
        unsigned int* ob = &Obuf[t * 16];
        #pragma unroll
        for (int m = 0; m < 4; ++m)
            #pragma unroll
            for (int tt = 0; tt < 2; ++tt) {
                unsigned int w0 = (unsigned int)f2bf(acc0[m][tt][0]) | ((unsigned int)f2bf(acc0[m][tt][1]) << 16);
                unsigned int w1 = (unsigned int)f2bf(acc0[m][tt][2]) | ((unsigned int)f2bf(acc0[m][tt][3]) << 16);
                ob[m * 4 + tt * 2 + 0] = w0;
                ob[m * 4 + tt * 2 + 1] = w1;
            }
    }

    // ---------------- Q-phase: query = geo@Wq + bq (reuses acc0) ----------------
    {
        float b0 = bq[w * 32 + cl], b1 = bq[w * 32 + 16 + cl];
        #pragma unroll
        for (int m = 0; m < 4; ++m) {
            acc0[m][0] = (f32x4){b0, b0, b0, b0};
            acc0[m][1] = (f32x4){b1, b1, b1, b1};
        }
        #pragma unroll
        for (int ks = 0; ks < 8; ++ks) {
            short8 a[4];
            #pragma unroll
            for (int m = 0; m < 4; ++m)
                a[m] = *(const short8*)&Abuf[(m * 16 + cl) * LDA + ks * 32 + cq * 8];
            short8 bw[2];
            #pragma unroll
            for (int tt = 0; tt < 2; ++tt)
                bw[tt] = *(const short8*)&wqf[(((w * 2 + tt) * 8 + ks) * 64 + l) * 8];
            #pragma unroll
            for (int m = 0; m < 4; ++m)
                #pragma unroll
                for (int tt = 0; tt < 2; ++tt)
                    acc0[m][tt] = __builtin_amdgcn_mfma_f32_16x16x32_bf16(a[m], bw[tt], acc0[m][tt], 0, 0, 0);
        }
    }
    __syncthreads();   // B2: all geo reads done

    // ---------------- stage non_geo = bf16([desc[sub] | desc[obj]]) ----------------
    {
        #pragma unroll
        for (int i = 0; i < 16; ++i) {
            int e = wu + 4 * i;
            int si = sub[e0 + e];
            int oi = obj[e0 + e];
            int idx = half ? oi : si;
            f32x4 v = *(const f32x4*)(desc + (long)idx * HD + ci * 4);
            ushort4 o;
            o.x = f2bf(v[0]); o.y = f2bf(v[1]); o.z = f2bf(v[2]); o.w = f2bf(v[3]);
            *(ushort4*)&Abuf[e * LDA + half * HD + ci * 4] = o;
        }
    }
    __syncthreads();   // B3

    // ---------------- K-phase: key = non_geo@Wk + bk -> acc1; S = Q.*K in acc0 ----------------
    {
        float b0 = bk[w * 32 + cl], b1 = bk[w * 32 + 16 + cl];
        #pragma unroll
        for (int m = 0; m < 4; ++m) {
            acc1[m][0] = (f32x4){b0, b0, b0, b0};
            acc1[m][1] = (f32x4){b1, b1, b1, b1};
        }
        #pragma unroll
        for (int ks = 0; ks < 8; ++ks) {
            short8 a[4];
            #pragma unroll
            for (int m = 0; m < 4; ++m)
                a[m] = *(const short8*)&Abuf[(m * 16 + cl) * LDA + ks * 32 + cq * 8];
            short8 bw[2];
            #pragma unroll
            for (int tt = 0; tt < 2; ++tt)
                bw[tt] = *(const short8*)&wkf[(((w * 2 + tt) * 8 + ks) * 64 + l) * 8];
            #pragma unroll
            for (int m = 0; m < 4; ++m)
                #pragma unroll
                for (int tt = 0; tt < 2; ++tt)
                    acc1[m][tt] = __builtin_amdgcn_mfma_f32_16x16x32_bf16(a[m], bw[tt], acc1[m][tt], 0, 0, 0);
        }
        #pragma unroll
        for (int m = 0; m < 4; ++m)
            #pragma unroll
            for (int tt = 0; tt < 2; ++tt)
                acc0[m][tt] *= acc1[m][tt];     // S = q .* k (acc1 now free)
    }

    // ---------------- in-register softmax partials over this wave's 32 cols ----------------
    {
        #pragma unroll
        for (int m = 0; m < 4; ++m) {
            float vm[4], es[4];
            #pragma unroll
            for (int r = 0; r < 4; ++r) {
                float x = fmaxf(acc0[m][0][r], acc0[m][1][r]);
                x = fmaxf(x, __shfl_xor(x, 1));
                x = fmaxf(x, __shfl_xor(x, 2));
                x = fmaxf(x, __shfl_xor(x, 4));
                x = fmaxf(x, __shfl_xor(x, 8));
                vm[r] = x;
                float s = __expf(acc0[m][0][r] - x) + __expf(acc0[m][1][r] - x);
                s += __shfl_xor(s, 1);
                s += __shfl_xor(s, 2);
                s += __shfl_xor(s, 4);
                s += __shfl_xor(s, 8);
                es[r] = s;
            }
            if (cl == 0) {
                #pragma unroll
                for (int r = 0; r < 4; ++r) {
                    int row = m * 16 + cq * 4 + r;
                    smx[row * 4 + w] = vm[r];
                    ssm[row * 4 + w] = es[r];
                }
            }
        }
    }

    // ---------------- V-phase: value = non_geo@Wv + bv -> acc1 ----------------
    {
        float b0 = bv[w * 32 + cl], b1 = bv[w * 32 + 16 + cl];
        #pragma unroll
        for (int m = 0; m < 4; ++m) {
            acc1[m][0] = (f32x4){b0, b0, b0, b0};
            acc1[m][1] = (f32x4){b1, b1, b1, b1};
        }
        #pragma unroll
        for (int ks = 0; ks < 8; ++ks) {
            short8 a[4];
            #pragma unroll
            for (int m = 0; m < 4; ++m)
                a[m] = *(const short8*)&Abuf[(m * 16 + cl) * LDA + ks * 32 + cq * 8];
            short8 bw[2];
            #pragma unroll
            for (int tt = 0; tt < 2; ++tt)
                bw[tt] = *(const short8*)&wvf[(((w * 2 + tt) * 8 + ks) * 64 + l) * 8];
            #pragma unroll
            for (int m = 0; m < 4; ++m)
                #pragma unroll
                for (int tt = 0; tt < 2; ++tt)
                    acc1[m][tt] = __builtin_amdgcn_mfma_f32_16x16x32_bf16(a[m], bw[tt], acc1[m][tt], 0, 0, 0);
        }
    }
    __syncthreads();   // B4: non_geo reads done, softmax partials written

    // ---------------- fused = V*alpha + O -> LDS bf16 (A-layout) ----------------
    {
        unsigned short* fusedBuf = Abuf;   // stride LDF
        const unsigned int* ob = &Obuf[t * 16];
        unsigned int ow[16];
        #pragma unroll
        for (int i = 0; i < 4; ++i) {
            uint4 v = ((const uint4*)ob)[i];
            ow[4 * i] = v.x; ow[4 * i + 1] = v.y; ow[4 * i + 2] = v.z; ow[4 * i + 3] = v.w;
        }
        #pragma unroll
        for (int m = 0; m < 4; ++m)
            #pragma unroll
            for (int r = 0; r < 4; ++r) {
                int row = m * 16 + cq * 4 + r;
                f32x4 a = *(const f32x4*)&smx[row * 4];
                f32x4 b = *(const f32x4*)&ssm[row * 4];
                float gm = fmaxf(fmaxf(a[0], a[1]), fmaxf(a[2], a[3]));
                float sm = b[0] * __expf(a[0] - gm) + b[1] * __expf(a[1] - gm)
                         + b[2] * __expf(a[2] - gm) + b[3] * __expf(a[3] - gm);
                float inv = 1.0f / sm;
                #pragma unroll
                for (int tt = 0; tt < 2; ++tt) {
                    unsigned int word = ow[m * 4 + tt * 2 + (r >> 1)];
                    unsigned short us = (r & 1) ? (unsigned short)(word >> 16) : (unsigned short)(word & 0xffffu);
                    float Oval = bf2f(us);
                    float alpha = __expf(acc0[m][tt][r] - gm) * inv;
                    float f = acc1[m][tt][r] * alpha + Oval;
                    fusedBuf[row * LDF + w * 32 + tt * 16 + cl] = f2bf(f);
                }
            }
    }
    __syncthreads();   // B5

    // ---------------- classifier L1: [64,128]@[128,64] + relu ----------------
    {
        const unsigned short* fusedBuf = Abuf;
        float b1 = bc1[w * 16 + cl];
        f32x4 acc[4];
        #pragma unroll
        for (int m = 0; m < 4; ++m) acc[m] = (f32x4){b1, b1, b1, b1};
        #pragma unroll
        for (int ks = 0; ks < 4; ++ks) {
            short8 a[4];
            #pragma unroll
            for (int m = 0; m < 4; ++m)
                a[m] = *(const short8*)&fusedBuf[(m * 16 + cl) * LDF + ks * 32 + cq * 8];
            short8 bw = *(const short8*)&wc1f[((w * 4 + ks) * 64 + l) * 8];
            #pragma unroll
            for (int m = 0; m < 4; ++m)
                acc[m] = __builtin_amdgcn_mfma_f32_16x16x32_bf16(a[m], bw, acc[m], 0, 0, 0);
        }
        #pragma unroll
        for (int m = 0; m < 4; ++m)
            #pragma unroll
            for (int r = 0; r < 4; ++r)
                h1Buf[(m * 16 + cq * 4 + r) * LDH1 + w * 16 + cl] = f2bf(fmaxf(acc[m][r], 0.f));
    }
    __syncthreads();   // B6

    // ---------------- classifier L2: [64,64]@[64,32] (no relu) ----------------
    {
        int tn = w & 1, mh = w >> 1;
        float b2 = bc2[tn * 16 + cl];
        f32x4 acc[2];
        acc[0] = (f32x4){b2, b2, b2, b2};
        acc[1] = (f32x4){b2, b2, b2, b2};
        #pragma unroll
        for (int ks = 0; ks < 2; ++ks) {
            short8 a[2];
            #pragma unroll
            for (int mm = 0; mm < 2; ++mm)
                a[mm] = *(const short8*)&h1Buf[((mh * 2 + mm) * 16 + cl) * LDH1 + ks * 32 + cq * 8];
            short8 bw = *(const short8*)&wc2f[((tn * 2 + ks) * 64 + l) * 8];
            #pragma unroll
            for (int mm = 0; mm < 2; ++mm)
                acc[mm] = __builtin_amdgcn_mfma_f32_16x16x32_bf16(a[mm], bw, acc[mm], 0, 0, 0);
        }
        #pragma unroll
        for (int mm = 0; mm < 2; ++mm)
            #pragma unroll
            for (int r = 0; r < 4; ++r)
                h2Buf[((mh * 2 + mm) * 16 + cq * 4 + r) * LDH2 + tn * 16 + cl] = f2bf(acc[mm][r]);
    }
    __syncthreads();   // B7

    // ---------------- classifier L3: [64,32]@[32,26] -> out (fp32) ----------------
    {
        f32x4 acc[2];
        #pragma unroll
        for (int tt = 0; tt < 2; ++tt) {
            int col = tt * 16 + cl;
            float b3 = (col < 26) ? bc3[col] : 0.f;
            acc[tt] = (f32x4){b3, b3, b3, b3};
        }
        short8 a = *(const short8*)&h2Buf[(w * 16 + cl) * LDH2 + cq * 8];
        #pragma unroll
        for (int tt = 0; tt < 2; ++tt)
            acc[tt] = __builtin_amdgcn_mfma_f32_16x16x32_bf16(a, *(const short8*)&wc3f[(tt * 64 + l) * 8], acc[tt], 0, 0, 0);
        #pragma unroll
        for (int tt = 0; tt < 2; ++tt) {
            int col = tt * 16 + cl;
            if (col < 26) {
                #pragma unroll
                for (int r = 0; r < 4; ++r) {
                    long row = e0 + w * 16 + cq * 4 + r;
                    out[row * 26 + col] = acc[tt][r];
                }
            }
        }
    }
}

extern "C" void kernel_launch(void* const* d_in, const int* in_sizes, int n_in,
                              void* d_out, int out_size, void* d_ws, size_t ws_size,
                              hipStream_t stream) {
    const float* nf   = (const float*)d_in[0];
    const float* desc = (const float*)d_in[1];
    const int* sub = (const int*)d_in[2];
    const int* obj = (const int*)d_in[3];
    const float* We  = (const float*)d_in[4];
    const float* be  = (const float*)d_in[5];
    const float* Wq  = (const float*)d_in[6];
    const float* bq  = (const float*)d_in[7];
    const float* Wk  = (const float*)d_in[8];
    const float* bk  = (const float*)d_in[9];
    const float* Wv  = (const float*)d_in[10];
    const float* bv  = (const float*)d_in[11];
    const float* Wc1 = (const float*)d_in[12];
    const float* bc1 = (const float*)d_in[13];
    const float* Wc2 = (const float*)d_in[14];
    const float* bc2 = (const float*)d_in[15];
    const float* Wc3 = (const float*)d_in[16];
    const float* bc3 = (const float*)d_in[17];

    unsigned short* ws = (unsigned short*)d_ws;
    unsigned short* wef  = ws;                 // 8*8*64*8  = 32768 elems
    unsigned short* wqf  = ws + 32768;
    unsigned short* wkf  = ws + 65536;
    unsigned short* wvf  = ws + 98304;
    unsigned short* wc1f = ws + 131072;        // 4*4*64*8 = 8192
    unsigned short* wc2f = ws + 139264;        // 2*2*64*8 = 2048
    unsigned short* wc3f = ws + 141312;        // 1*2*64*8 = 1024

    pack_all<<<556, 256, 0, stream>>>(We, Wq, Wk, Wv, Wc1, Wc2, Wc3, ws);

    fused_relcls<<<NEDGE / TM, 256, 0, stream>>>(
        nf, desc, sub, obj,
        wef, wqf, wkf, wvf, wc1f, wc2f, wc3f,
        be, bq, bk, bv, bc1, bc2, bc3,
        (float*)d_out);
}